// Round 9
// baseline (104.474 us; speedup 1.0000x reference)
//
#include <hip/hip_runtime.h>
#include <hip/hip_bf16.h>

// Problem constants
#define B_   32
#define N_   2048
#define E_   768
#define OUT_ 384
#define HID_ 16
constexpr int ROWS   = B_ * N_;      // 65536
constexpr int TILE_M = 16;           // rows per block
constexpr int NT     = OUT_ / 16;    // 24 N-tiles of local GEMM
constexpr int KT_L   = 6;            // 6 K-steps (local, K=192)
constexpr int KT_G   = 24;           // 24 K-steps (gate, K=768)

typedef __attribute__((ext_vector_type(8))) short bf16x8;
typedef __attribute__((ext_vector_type(4))) float f32x4;

__device__ __forceinline__ short f2bf(float f) {
  __hip_bfloat16 h = __float2bfloat16(f);          // RNE hardware cvt
  return __builtin_bit_cast(short, h);
}

// Abramowitz-Stegun 7.1.26, |err| <= 1.5e-7, branch-free
__device__ __forceinline__ float fast_erf(float x) {
  const float ax = __builtin_fabsf(x);
  const float t  = __builtin_amdgcn_rcpf(__builtin_fmaf(0.3275911f, ax, 1.0f));
  float p = __builtin_fmaf(1.061405429f, t, -1.453152027f);
  p = __builtin_fmaf(p, t, 1.421413741f);
  p = __builtin_fmaf(p, t, -0.284496736f);
  p = __builtin_fmaf(p, t, 0.254829592f);
  const float e = __expf(-ax * ax);
  const float y = __builtin_fmaf(-p * t, e, 1.0f);
  return __builtin_copysignf(y, x);
}
__device__ __forceinline__ float gelu(float v) {
  return 0.5f * v * (1.0f + fast_erf(v * 0.70710678118654752f));
}

// ---------------- pre-pass: build bf16 MFMA B-fragments in workspace ----------------
__global__ void prep_kernel(const float* __restrict__ w_l, const float* __restrict__ w_g1,
                            short* __restrict__ wsL, short* __restrict__ wsG) {
  int t = blockIdx.x * blockDim.x + threadIdx.x;
  int wave = t >> 6, ln = t & 63;
  int kg = ln >> 4, c16 = ln & 15;
  if (wave < NT * KT_L) {
    int n = wave / KT_L, ks = wave % KT_L;
    bf16x8 v;
#pragma unroll
    for (int j = 0; j < 8; ++j) {
      int k = ks * 32 + kg * 8 + j;
      v[j] = f2bf(w_l[k * OUT_ + n * 16 + c16]);
    }
    *reinterpret_cast<bf16x8*>(&wsL[(size_t)(wave * 64 + ln) * 8]) = v;
  } else if (wave < NT * KT_L + KT_G) {
    int ks = wave - NT * KT_L;
    bf16x8 v;
#pragma unroll
    for (int j = 0; j < 8; ++j) {
      int k = ks * 32 + kg * 8 + j;
      v[j] = f2bf(w_g1[k * HID_ + c16]);
    }
    *reinterpret_cast<bf16x8*>(&wsG[(size_t)(ks * 64 + ln) * 8]) = v;
  }
}

// ---------------- main fused kernel: 256 threads = 4 waves own 16 rows ----------------
// x tile staged via global_load_lds (deep vmcnt queue), XOR-swizzled via pre-swizzled
// global source (linear LDS dest), reads apply the same XOR.
template <bool USE_WS>
__global__ __launch_bounds__(256, 3)
void spectre_kernel(const float* __restrict__ x,
                    const float* __restrict__ w_g1, const float* __restrict__ b_g1,
                    const float* __restrict__ ln_g_w, const float* __restrict__ ln_g_b,
                    const float* __restrict__ w_g2, const float* __restrict__ b_g2,
                    const float* __restrict__ w_l, const float* __restrict__ b_l,
                    const float* __restrict__ ln_l_w, const float* __restrict__ ln_l_b,
                    const short* __restrict__ wsL, const short* __restrict__ wsG,
                    float* __restrict__ out) {
  __shared__ float xs[TILE_M * E_];      // 49152 B: x tile f32, rows swizzled by XOR(row&7)<<4
  __shared__ float red2[4][16][17];      // 4352 B: gate partial sums per wave (padded)
  __shared__ float reds[4][16][2];       // 512 B : local LN partials per wave

  const int tid = threadIdx.x;
  const int wv  = tid >> 6;        // wave 0..3
  const int ln  = tid & 63;        // lane
  const int kg  = ln >> 4;         // k-group / D-row group
  const int l15 = ln & 15;         // A-row / D-col
  const int row0 = blockIdx.x * TILE_M;

  const float* xb = x + (size_t)row0 * E_;

  // ---- issue 12 async global->LDS loads per thread-wave (wave wv: rows 4wv..4wv+3) ----
  // LDS dest linear (base + lane*16); global source pre-XOR-swizzled within the row.
#pragma unroll
  for (int r = 0; r < 4; ++r) {
    const int row = wv * 4 + r;
    const int swz = (row & 7) << 4;
#pragma unroll
    for (int t = 0; t < 3; ++t) {
      const char* g = (const char*)xb + row * 3072 + ((t * 1024 + ln * 16) ^ swz);
      __builtin_amdgcn_global_load_lds(
          (const __attribute__((address_space(1))) void*)g,
          (__attribute__((address_space(3))) void*)((char*)xs + row * 3072 + t * 1024),
          16, 0, 0);
    }
  }

  // ---- preload gate B frags + per-lane consts (in flight during stage) ----
  bf16x8 gbv[6];
  if constexpr (USE_WS) {
#pragma unroll
    for (int i = 0; i < 6; ++i)
      gbv[i] = *reinterpret_cast<const bf16x8*>(&wsG[((wv * 6 + i) * 64 + ln) * 8]);
  } else {
#pragma unroll
    for (int i = 0; i < 6; ++i) {
      const int ks = wv * 6 + i;
#pragma unroll
      for (int j = 0; j < 8; ++j) gbv[i][j] = f2bf(w_g1[(ks * 32 + kg * 8 + j) * HID_ + l15]);
    }
  }
  const float bg  = b_g1[l15];
  const float lgw = ln_g_w[l15];
  const float lgb = ln_g_b[l15];
  const float wg2 = w_g2[l15];
  const float bg2 = b_g2[0];
  float blv[6], lwv[6], lbv[6];
#pragma unroll
  for (int j = 0; j < 6; ++j) {
    const int col = (wv * 6 + j) * 16 + l15;
    blv[j] = b_l[col];
    lwv[j] = ln_l_w[col];
    lbv[j] = ln_l_b[col];
  }

  asm volatile("s_waitcnt vmcnt(0)" ::: "memory");
  __syncthreads();   // x tile resident (all waves)

  const char* xc = (const char*)xs;
  const int rb   = l15 * 3072;
  const int swzl = (l15 & 7) << 4;

  // ---- gate GEMM partial: wave wv owns K-steps [6wv, 6wv+6) ----
  f32x4 accg = {0.f, 0.f, 0.f, 0.f};
#pragma unroll
  for (int i = 0; i < 6; ++i) {
    const int ks = wv * 6 + i;
    const int b0 = ks * 128 + kg * 32;
    const float4 u0 = *reinterpret_cast<const float4*>(xc + rb + (b0 ^ swzl));
    const float4 u1 = *reinterpret_cast<const float4*>(xc + rb + ((b0 + 16) ^ swzl));
    const bf16x8 a = { f2bf(u0.x), f2bf(u0.y), f2bf(u0.z), f2bf(u0.w),
                       f2bf(u1.x), f2bf(u1.y), f2bf(u1.z), f2bf(u1.w) };
    accg = __builtin_amdgcn_mfma_f32_16x16x32_bf16(a, gbv[i], accg, 0, 0, 0);
  }
#pragma unroll
  for (int r = 0; r < 4; ++r) red2[wv][kg * 4 + r][l15] = accg[r];

  // ---- local A fragments from LDS tile (x cols that are multiples of 4) ----
  bf16x8 aL[KT_L];
#pragma unroll
  for (int ks = 0; ks < KT_L; ++ks) {
#pragma unroll
    for (int j = 0; j < 8; ++j) {
      const float v = *reinterpret_cast<const float*>(
          xc + rb + ((ks * 512 + kg * 128 + j * 16) ^ swzl));
      aL[ks][j] = f2bf(v);
    }
  }

  // ---- preload local B group ks=0 (wave's 6 n-tiles) ----
  bf16x8 bc[6], bn[6];
#pragma unroll
  for (int j = 0; j < 6; ++j) {
    if constexpr (USE_WS) {
      bc[j] = *reinterpret_cast<const bf16x8*>(&wsL[(((wv * 6 + j) * KT_L + 0) * 64 + ln) * 8]);
    } else {
#pragma unroll
      for (int jj = 0; jj < 8; ++jj)
        bc[j][jj] = f2bf(w_l[(kg * 8 + jj) * OUT_ + (wv * 6 + j) * 16 + l15]);
    }
  }

  __syncthreads();   // red2 visible

  // ---- gate finalize: combine 4 wave partials, LN over 16, GeLU, dot w_g2 ----
  float gf[4];
#pragma unroll
  for (int r = 0; r < 4; ++r) {
    const int row = kg * 4 + r;
    const float y = red2[0][row][l15] + red2[1][row][l15] +
                    red2[2][row][l15] + red2[3][row][l15] + bg;
    float s = y, q = y * y;
#pragma unroll
    for (int m = 1; m < 16; m <<= 1) {
      s += __shfl_xor(s, m);
      q += __shfl_xor(q, m);
    }
    const float mean = s * (1.f / 16.f);
    const float var  = q * (1.f / 16.f) - mean * mean;
    const float rstd = rsqrtf(var + 1e-5f);
    const float vn = (y - mean) * rstd * lgw + lgb;
    float ps = gelu(vn) * wg2;
#pragma unroll
    for (int m = 1; m < 16; m <<= 1) ps += __shfl_xor(ps, m);
    gf[r] = ps + bg2;
  }

  // ---- local GEMM: ks-outer, ping-pong prefetch of next K-group ----
  f32x4 acc[6];
#pragma unroll
  for (int j = 0; j < 6; ++j) acc[j] = (f32x4){0.f, 0.f, 0.f, 0.f};
#pragma unroll
  for (int ks = 0; ks < KT_L; ++ks) {
    if (ks + 1 < KT_L) {
#pragma unroll
      for (int j = 0; j < 6; ++j) {
        if constexpr (USE_WS) {
          bn[j] = *reinterpret_cast<const bf16x8*>(
              &wsL[(((wv * 6 + j) * KT_L + ks + 1) * 64 + ln) * 8]);
        } else {
#pragma unroll
          for (int jj = 0; jj < 8; ++jj)
            bn[j][jj] = f2bf(w_l[((ks + 1) * 32 + kg * 8 + jj) * OUT_ + (wv * 6 + j) * 16 + l15]);
        }
      }
    }
#pragma unroll
    for (int j = 0; j < 6; ++j)
      acc[j] = __builtin_amdgcn_mfma_f32_16x16x32_bf16(aL[ks], bc[j], acc[j], 0, 0, 0);
#pragma unroll
    for (int j = 0; j < 6; ++j) bc[j] = bn[j];
  }

  // ---- add b_l, per-row LN stats over this wave's 96 cols ----
  float s1[4] = {0.f, 0.f, 0.f, 0.f}, s2[4] = {0.f, 0.f, 0.f, 0.f};
#pragma unroll
  for (int j = 0; j < 6; ++j) {
#pragma unroll
    for (int r = 0; r < 4; ++r) {
      const float v = acc[j][r] + blv[j];
      acc[j][r] = v;
      s1[r] += v;
      s2[r] += v * v;
    }
  }
#pragma unroll
  for (int m = 1; m < 16; m <<= 1) {
#pragma unroll
    for (int r = 0; r < 4; ++r) {
      s1[r] += __shfl_xor(s1[r], m);
      s2[r] += __shfl_xor(s2[r], m);
    }
  }
  if (l15 == 0) {
#pragma unroll
    for (int r = 0; r < 4; ++r) {
      reds[wv][kg * 4 + r][0] = s1[r];
      reds[wv][kg * 4 + r][1] = s2[r];
    }
  }
  __syncthreads();

  // ---- local finalize: LN over 384 (4-wave combine), GeLU, + pooled (f32 LDS) + gate ----
  float meanr[4], rstdr[4];
#pragma unroll
  for (int r = 0; r < 4; ++r) {
    const int row = kg * 4 + r;
    const float t1 = reds[0][row][0] + reds[1][row][0] + reds[2][row][0] + reds[3][row][0];
    const float t2 = reds[0][row][1] + reds[1][row][1] + reds[2][row][1] + reds[3][row][1];
    meanr[r] = t1 * (1.f / 384.f);
    const float var = t2 * (1.f / 384.f) - meanr[r] * meanr[r];
    rstdr[r] = rsqrtf(var + 1e-5f);
  }
#pragma unroll
  for (int j = 0; j < 6; ++j) {
    const int col = (wv * 6 + j) * 16 + l15;
#pragma unroll
    for (int r = 0; r < 4; ++r) {
      const int row = kg * 4 + r;
      const float2 px = *reinterpret_cast<const float2*>(
          (const char*)xs + row * 3072 + ((col * 8) ^ ((row & 7) << 4)));
      const float pooled = 0.5f * (px.x + px.y);
      const float vn = (acc[j][r] - meanr[r]) * rstdr[r] * lwv[j] + lbv[j];
      out[(size_t)(row0 + row) * OUT_ + col] = gelu(vn) + gf[r] + pooled;
    }
  }
}

// ---------------- launch ----------------
extern "C" void kernel_launch(void* const* d_in, const int* in_sizes, int n_in,
                              void* d_out, int out_size, void* d_ws, size_t ws_size,
                              hipStream_t stream) {
  (void)in_sizes; (void)n_in; (void)out_size;
  const float* x      = (const float*)d_in[0];
  const float* w_g1   = (const float*)d_in[1];
  const float* b_g1   = (const float*)d_in[2];
  const float* ln_g_w = (const float*)d_in[3];
  const float* ln_g_b = (const float*)d_in[4];
  const float* w_g2   = (const float*)d_in[5];
  const float* b_g2   = (const float*)d_in[6];
  const float* w_l    = (const float*)d_in[7];
  const float* b_l    = (const float*)d_in[8];
  const float* ln_l_w = (const float*)d_in[9];
  const float* ln_l_b = (const float*)d_in[10];
  float* out = (float*)d_out;

  const size_t needL = (size_t)NT * KT_L * 64 * 8;   // shorts
  const size_t needG = (size_t)KT_G * 64 * 8;        // shorts
  const bool use_ws = ws_size >= (needL + needG) * sizeof(short);

  short* wsL = (short*)d_ws;
  short* wsG = wsL + needL;

  const int grid = ROWS / TILE_M;   // 4096
  if (use_ws) {
    prep_kernel<<<(NT * KT_L + KT_G) * 64 / 256, 256, 0, stream>>>(w_l, w_g1, wsL, wsG);
    spectre_kernel<true><<<grid, 256, 0, stream>>>(x, w_g1, b_g1, ln_g_w, ln_g_b, w_g2, b_g2,
                                                   w_l, b_l, ln_l_w, ln_l_b, wsL, wsG, out);
  } else {
    spectre_kernel<false><<<grid, 256, 0, stream>>>(x, w_g1, b_g1, ln_g_w, ln_g_b, w_g2, b_g2,
                                                    w_l, b_l, ln_l_w, ln_l_b, nullptr, nullptr, out);
  }
}